// Round 8
// baseline (115.099 us; speedup 1.0000x reference)
//
#include <hip/hip_runtime.h>

#define NROW 200000
#define RDIM 32
#define BATCH 131072
#define STEP 0.01f
#define CAP 8                      // bucket capacity; Poisson(0.655) tail > 8 ~ 3e-8/row
#define HALFROWS (3 * NROW / 2)    // 300000

// ===========================================================================
// FAST PATH ws layout (~43.4 MB), all 8B-aligned:
//   cnt    int[3*NROW]      \ one contiguous memset(0)
//   head   int[3*NROW]      /  (head uses idx+1 encoding; 0 = empty)
//   nxt    int[3*BATCH]
//   bucket int[3*NROW*CAP]
//   scal   float2[BATCH]    (A = ki - phi*wi, wi)
//   Lp     float[BATCH*32]  (L_r * g0*g1*g2)
// ===========================================================================

// Merged precompute + bucket build. 8 lanes per batch element, float4 I/O.
__global__ __launch_bounds__(256) void em_pre_bkt(
    const float* __restrict__ U0, const float* __restrict__ U1,
    const float* __restrict__ U2, const float* __restrict__ L,
    const float* __restrict__ bv, const int* __restrict__ be,
    int* __restrict__ cnt, int* __restrict__ head, int* __restrict__ nxt,
    int* __restrict__ bucket, float2* __restrict__ scal, float* __restrict__ LpBuf)
{
    int tid = blockIdx.x * blockDim.x + threadIdx.x;
    int i   = tid >> 3;          // batch element
    int sub = tid & 7;           // 4-float slot
    if (i >= BATCH) return;

    int e0 = be[i * 3 + 0];
    int e1 = be[i * 3 + 1];
    int e2 = be[i * 3 + 2];

    float4 g0 = *(const float4*)(U0 + (size_t)e0 * RDIM + sub * 4);
    float4 g1 = *(const float4*)(U1 + (size_t)e1 * RDIM + sub * 4);
    float4 g2 = *(const float4*)(U2 + (size_t)e2 * RDIM + sub * 4);
    float4 Lv = *(const float4*)(L + sub * 4);

    float4 Lp;
    Lp.x = Lv.x * g0.x * g1.x * g2.x;
    Lp.y = Lv.y * g0.y * g1.y * g2.y;
    Lp.z = Lv.z * g0.z * g1.z * g2.z;
    Lp.w = Lv.w * g0.w * g1.w * g2.w;

    float phi = (Lp.x + Lp.y) + (Lp.z + Lp.w);
    phi += __shfl_xor(phi, 1);
    phi += __shfl_xor(phi, 2);
    phi += __shfl_xor(phi, 4);

    float wi = 0.5f / phi * tanhf(0.5f * phi);

    *(float4*)(LpBuf + (size_t)i * RDIM + sub * 4) = Lp;

    if (sub == 0) {
        float A = (bv[i] - 0.5f) - phi * wi;
        scal[i] = make_float2(A, wi);
    }
    if (sub < 3) {
        int row = (sub == 0) ? e0 : (sub == 1) ? e1 : e2;
        int rid = sub * NROW + row;
        int slot = atomicAdd(&cnt[rid], 1);
        if (slot < CAP) {
            bucket[(size_t)rid * CAP + slot] = i;
        } else {
            int idx = i * 3 + sub;                       // idx+1 encoding
            nxt[idx] = atomicExch(&head[rid], idx + 1);
        }
    }
}

// 2 rows per thread (rid, rid+HALFROWS); all loads for both rows burst-issued.
__global__ __launch_bounds__(256) void em_apply_x2(
    const float* __restrict__ U0, const float* __restrict__ U1,
    const float* __restrict__ U2,
    const float* __restrict__ S0, const float* __restrict__ S1,
    const float* __restrict__ S2,
    const float* __restrict__ T0, const float* __restrict__ T1,
    const float* __restrict__ T2,
    const int* __restrict__ cnt, const int* __restrict__ head,
    const int* __restrict__ nxt, const int* __restrict__ bucket,
    const float2* __restrict__ scal, const float* __restrict__ LpBuf,
    float* __restrict__ out)
{
    int tid = blockIdx.x * blockDim.x + threadIdx.x;
    int sub = tid & 7;
    int ra  = tid >> 3;              // [0, HALFROWS)
    if (ra >= HALFROWS) return;
    int rb  = ra + HALFROWS;

    int da = ra / NROW, rowa = ra - da * NROW;   // da in {0,1}; block-uniform
    int db = rb / NROW, rowb = rb - db * NROW;   // db in {1,2}; block-uniform

    const float* Uda = (da == 0) ? U0 : (da == 1) ? U1 : U2;
    const float* Ssa = (da == 0) ? S0 : (da == 1) ? S1 : S2;
    const float* Tsa = (da == 0) ? T0 : (da == 1) ? T1 : T2;
    const float* Udb = (db == 0) ? U0 : (db == 1) ? U1 : U2;
    const float* Ssb = (db == 0) ? S0 : (db == 1) ? S1 : S2;
    const float* Tsb = (db == 0) ? T0 : (db == 1) ? T1 : T2;

    size_t offa = (size_t)rowa * RDIM + sub * 4;
    size_t offb = (size_t)rowb * RDIM + sub * 4;

    // ---------------- level-1 burst (all independent) ----------------
    int    na   = cnt[ra];
    int    nb   = cnt[rb];
    int4   bka  = *(const int4*)(bucket + (size_t)ra * CAP);
    int4   bkb  = *(const int4*)(bucket + (size_t)rb * CAP);
    float4 sina = *(const float4*)(Ssa + offa);
    float4 tina = *(const float4*)(Tsa + offa);
    float4 sinb = *(const float4*)(Ssb + offb);
    float4 tinb = *(const float4*)(Tsb + offb);
    float4 gda  = *(const float4*)(Uda + offa);   // unconditional: level-1, real data
    float4 gdb  = *(const float4*)(Udb + offb);

    // ---------------- level-2 burst (depends only on cnt/bucket) ----
    int a0 = (na > 0) ? bka.x : 0;
    int a1 = (na > 1) ? bka.y : 0;
    int a2 = (na > 2) ? bka.z : 0;
    int a3 = (na > 3) ? bka.w : 0;
    int b0 = (nb > 0) ? bkb.x : 0;
    int b1 = (nb > 1) ? bkb.y : 0;
    int b2 = (nb > 2) ? bkb.z : 0;
    int b3 = (nb > 3) ? bkb.w : 0;

    float2 awa0 = scal[a0], awa1 = scal[a1], awa2 = scal[a2], awa3 = scal[a3];
    float2 awb0 = scal[b0], awb1 = scal[b1], awb2 = scal[b2], awb3 = scal[b3];
    float4 pa0 = *(const float4*)(LpBuf + (size_t)a0 * RDIM + sub * 4);
    float4 pa1 = *(const float4*)(LpBuf + (size_t)a1 * RDIM + sub * 4);
    float4 pa2 = *(const float4*)(LpBuf + (size_t)a2 * RDIM + sub * 4);
    float4 pa3 = *(const float4*)(LpBuf + (size_t)a3 * RDIM + sub * 4);
    float4 pb0 = *(const float4*)(LpBuf + (size_t)b0 * RDIM + sub * 4);
    float4 pb1 = *(const float4*)(LpBuf + (size_t)b1 * RDIM + sub * 4);
    float4 pb2 = *(const float4*)(LpBuf + (size_t)b2 * RDIM + sub * 4);
    float4 pb3 = *(const float4*)(LpBuf + (size_t)b3 * RDIM + sub * 4);

    // mask unused slots via zeroed weights (contributions become exact 0)
    if (na <= 1) { awa1.x = 0.f; awa1.y = 0.f; }
    if (na <= 2) { awa2.x = 0.f; awa2.y = 0.f; }
    if (na <= 3) { awa3.x = 0.f; awa3.y = 0.f; }
    if (nb <= 1) { awb1.x = 0.f; awb1.y = 0.f; }
    if (nb <= 2) { awb2.x = 0.f; awb2.y = 0.f; }
    if (nb <= 3) { awb3.x = 0.f; awb3.y = 0.f; }

    float4 rga, rgb;
    rga.x = __builtin_amdgcn_rcpf(gda.x);   // U in [0.05,1] — always valid
    rga.y = __builtin_amdgcn_rcpf(gda.y);
    rga.z = __builtin_amdgcn_rcpf(gda.z);
    rga.w = __builtin_amdgcn_rcpf(gda.w);
    rgb.x = __builtin_amdgcn_rcpf(gdb.x);
    rgb.y = __builtin_amdgcn_rcpf(gdb.y);
    rgb.z = __builtin_amdgcn_rcpf(gdb.z);
    rgb.w = __builtin_amdgcn_rcpf(gdb.w);

    float4 saa = make_float4(0.f, 0.f, 0.f, 0.f);
    float4 taa = make_float4(0.f, 0.f, 0.f, 0.f);
    float4 sab = make_float4(0.f, 0.f, 0.f, 0.f);
    float4 tab = make_float4(0.f, 0.f, 0.f, 0.f);

    #define ACC(SA, TA, RG, AW, P)                                      \
    {                                                                   \
        float cx = (P).x * (RG).x, cy = (P).y * (RG).y,                 \
              cz = (P).z * (RG).z, cw = (P).w * (RG).w;                 \
        (SA).x += (AW).y * cx * cx;  (SA).y += (AW).y * cy * cy;        \
        (SA).z += (AW).y * cz * cz;  (SA).w += (AW).y * cw * cw;        \
        (TA).x += ((AW).x + (AW).y * (P).x) * cx;                       \
        (TA).y += ((AW).x + (AW).y * (P).y) * cy;                       \
        (TA).z += ((AW).x + (AW).y * (P).z) * cz;                       \
        (TA).w += ((AW).x + (AW).y * (P).w) * cw;                       \
    }

    ACC(saa, taa, rga, awa0, pa0) ACC(saa, taa, rga, awa1, pa1)
    ACC(saa, taa, rga, awa2, pa2) ACC(saa, taa, rga, awa3, pa3)
    ACC(sab, tab, rgb, awb0, pb0) ACC(sab, tab, rgb, awb1, pb1)
    ACC(sab, tab, rgb, awb2, pb2) ACC(sab, tab, rgb, awb3, pb3)

    // cold tails (~6e-4 of rows)
    if (na > 4) {
        int m = (na < CAP) ? na : CAP;
        for (int j = 4; j < m; ++j) {
            int e = bucket[(size_t)ra * CAP + j];
            float2 aw = scal[e];
            float4 P  = *(const float4*)(LpBuf + (size_t)e * RDIM + sub * 4);
            ACC(saa, taa, rga, aw, P)
        }
        if (na > CAP) {
            int t = head[ra];
            while (t != 0) {
                int idx = t - 1;
                int e = idx / 3;
                float2 aw = scal[e];
                float4 P  = *(const float4*)(LpBuf + (size_t)e * RDIM + sub * 4);
                ACC(saa, taa, rga, aw, P)
                t = nxt[idx];
            }
        }
    }
    if (nb > 4) {
        int m = (nb < CAP) ? nb : CAP;
        for (int j = 4; j < m; ++j) {
            int e = bucket[(size_t)rb * CAP + j];
            float2 aw = scal[e];
            float4 P  = *(const float4*)(LpBuf + (size_t)e * RDIM + sub * 4);
            ACC(sab, tab, rgb, aw, P)
        }
        if (nb > CAP) {
            int t = head[rb];
            while (t != 0) {
                int idx = t - 1;
                int e = idx / 3;
                float2 aw = scal[e];
                float4 P  = *(const float4*)(LpBuf + (size_t)e * RDIM + sub * 4);
                ACC(sab, tab, rgb, aw, P)
                t = nxt[idx];
            }
        }
    }
    #undef ACC

    bool ta_ = (na > 0), tb_ = (nb > 0);
    float4 oSa, oTa, oSb, oTb;
    oSa.x = ta_ ? (1.0f - STEP) * sina.x + STEP * saa.x : sina.x;
    oSa.y = ta_ ? (1.0f - STEP) * sina.y + STEP * saa.y : sina.y;
    oSa.z = ta_ ? (1.0f - STEP) * sina.z + STEP * saa.z : sina.z;
    oSa.w = ta_ ? (1.0f - STEP) * sina.w + STEP * saa.w : sina.w;
    oTa.x = ta_ ? (1.0f - STEP) * tina.x + STEP * taa.x : tina.x;
    oTa.y = ta_ ? (1.0f - STEP) * tina.y + STEP * taa.y : tina.y;
    oTa.z = ta_ ? (1.0f - STEP) * tina.z + STEP * taa.z : tina.z;
    oTa.w = ta_ ? (1.0f - STEP) * tina.w + STEP * taa.w : tina.w;
    oSb.x = tb_ ? (1.0f - STEP) * sinb.x + STEP * sab.x : sinb.x;
    oSb.y = tb_ ? (1.0f - STEP) * sinb.y + STEP * sab.y : sinb.y;
    oSb.z = tb_ ? (1.0f - STEP) * sinb.z + STEP * sab.z : sinb.z;
    oSb.w = tb_ ? (1.0f - STEP) * sinb.w + STEP * sab.w : sinb.w;
    oTb.x = tb_ ? (1.0f - STEP) * tinb.x + STEP * tab.x : tinb.x;
    oTb.y = tb_ ? (1.0f - STEP) * tinb.y + STEP * tab.y : tinb.y;
    oTb.z = tb_ ? (1.0f - STEP) * tinb.z + STEP * tab.z : tinb.z;
    oTb.w = tb_ ? (1.0f - STEP) * tinb.w + STEP * tab.w : tinb.w;

    const size_t TOFF = (size_t)3 * NROW * RDIM;
    size_t oa = (size_t)ra * RDIM + sub * 4;   // S plane offset == rid*32
    size_t ob = (size_t)rb * RDIM + sub * 4;
    *(float4*)(out + oa)        = oSa;
    *(float4*)(out + TOFF + oa) = oTa;
    *(float4*)(out + ob)        = oSb;
    *(float4*)(out + TOFF + ob) = oTb;
}

// ===========================================================================
// FALLBACK (chain version) — used only if ws too small for buckets
// ===========================================================================
__global__ __launch_bounds__(256) void em_pre(
    const float* __restrict__ U0, const float* __restrict__ U1,
    const float* __restrict__ U2, const float* __restrict__ L,
    const float* __restrict__ bv, const int* __restrict__ be,
    int* __restrict__ head, int* __restrict__ nxt,
    float2* __restrict__ scal, float* __restrict__ LpBuf)
{
    int tid = blockIdx.x * blockDim.x + threadIdx.x;
    int i   = tid >> 3;
    int sub = tid & 7;
    if (i >= BATCH) return;

    int e0 = be[i * 3 + 0];
    int e1 = be[i * 3 + 1];
    int e2 = be[i * 3 + 2];

    float4 g0 = *(const float4*)(U0 + (size_t)e0 * RDIM + sub * 4);
    float4 g1 = *(const float4*)(U1 + (size_t)e1 * RDIM + sub * 4);
    float4 g2 = *(const float4*)(U2 + (size_t)e2 * RDIM + sub * 4);
    float4 Lv = *(const float4*)(L + sub * 4);

    float4 Lp;
    Lp.x = Lv.x * g0.x * g1.x * g2.x;
    Lp.y = Lv.y * g0.y * g1.y * g2.y;
    Lp.z = Lv.z * g0.z * g1.z * g2.z;
    Lp.w = Lv.w * g0.w * g1.w * g2.w;

    float phi = (Lp.x + Lp.y) + (Lp.z + Lp.w);
    phi += __shfl_xor(phi, 1);
    phi += __shfl_xor(phi, 2);
    phi += __shfl_xor(phi, 4);

    float wi = 0.5f / phi * tanhf(0.5f * phi);

    *(float4*)(LpBuf + (size_t)i * RDIM + sub * 4) = Lp;

    if (sub == 0) {
        float A = (bv[i] - 0.5f) - phi * wi;
        scal[i] = make_float2(A, wi);
    }
    if (sub < 3) {
        int row = (sub == 0) ? e0 : (sub == 1) ? e1 : e2;
        int idx = i * 3 + sub;
        nxt[idx] = atomicExch(&head[sub * NROW + row], idx + 1);
    }
}

__global__ __launch_bounds__(256) void em_apply_vec(
    const float* __restrict__ U0, const float* __restrict__ U1,
    const float* __restrict__ U2,
    const float* __restrict__ S0, const float* __restrict__ S1,
    const float* __restrict__ S2,
    const float* __restrict__ T0, const float* __restrict__ T1,
    const float* __restrict__ T2,
    const int* __restrict__ head, const int* __restrict__ nxt,
    const float2* __restrict__ scal, const float* __restrict__ LpBuf,
    float* __restrict__ out)
{
    int tid = blockIdx.x * blockDim.x + threadIdx.x;
    int rid = tid >> 3;
    int sub = tid & 7;
    if (rid >= 3 * NROW) return;

    int d   = rid / NROW;
    int row = rid - d * NROW;

    const float* Ud   = (d == 0) ? U0 : (d == 1) ? U1 : U2;
    const float* Ssrc = (d == 0) ? S0 : (d == 1) ? S1 : S2;
    const float* Tsrc = (d == 0) ? T0 : (d == 1) ? T1 : T2;

    size_t roff = (size_t)row * RDIM + sub * 4;
    float4 s_in = *(const float4*)(Ssrc + roff);
    float4 t_in = *(const float4*)(Tsrc + roff);

    int    t  = head[rid];
    float4 oS = s_in;
    float4 oT = t_in;

    if (t != 0) {
        float4 gd = *(const float4*)(Ud + roff);
        float4 rg;
        rg.x = __builtin_amdgcn_rcpf(gd.x);
        rg.y = __builtin_amdgcn_rcpf(gd.y);
        rg.z = __builtin_amdgcn_rcpf(gd.z);
        rg.w = __builtin_amdgcn_rcpf(gd.w);

        float4 sa = make_float4(0.f, 0.f, 0.f, 0.f);
        float4 ta = make_float4(0.f, 0.f, 0.f, 0.f);
        while (t != 0) {
            int idx = t - 1;
            int e = idx / 3;
            float2 aw = scal[e];
            float4 Lp = *(const float4*)(LpBuf + (size_t)e * RDIM + sub * 4);
            float cx = Lp.x * rg.x, cy = Lp.y * rg.y,
                  cz = Lp.z * rg.z, cw = Lp.w * rg.w;
            sa.x += aw.y * cx * cx;  sa.y += aw.y * cy * cy;
            sa.z += aw.y * cz * cz;  sa.w += aw.y * cw * cw;
            ta.x += (aw.x + aw.y * Lp.x) * cx;
            ta.y += (aw.x + aw.y * Lp.y) * cy;
            ta.z += (aw.x + aw.y * Lp.z) * cz;
            ta.w += (aw.x + aw.y * Lp.w) * cw;
            t = nxt[idx];
        }
        oS.x = (1.0f - STEP) * s_in.x + STEP * sa.x;
        oS.y = (1.0f - STEP) * s_in.y + STEP * sa.y;
        oS.z = (1.0f - STEP) * s_in.z + STEP * sa.z;
        oS.w = (1.0f - STEP) * s_in.w + STEP * sa.w;
        oT.x = (1.0f - STEP) * t_in.x + STEP * ta.x;
        oT.y = (1.0f - STEP) * t_in.y + STEP * ta.y;
        oT.z = (1.0f - STEP) * t_in.z + STEP * ta.z;
        oT.w = (1.0f - STEP) * t_in.w + STEP * ta.w;
    }

    size_t offS = ((size_t)d * NROW + row) * RDIM + sub * 4;
    *(float4*)(out + offS) = oS;
    *(float4*)(out + (size_t)3 * NROW * RDIM + offS) = oT;
}

// ===========================================================================
extern "C" void kernel_launch(void* const* d_in, const int* in_sizes, int n_in,
                              void* d_out, int out_size, void* d_ws, size_t ws_size,
                              hipStream_t stream)
{
    // setup_inputs() insertion order: U0,S0,T0, U1,S1,T1, U2,S2,T2, L, bv, be
    const float* U0 = (const float*)d_in[0];
    const float* S0 = (const float*)d_in[1];
    const float* T0 = (const float*)d_in[2];
    const float* U1 = (const float*)d_in[3];
    const float* S1 = (const float*)d_in[4];
    const float* T1 = (const float*)d_in[5];
    const float* U2 = (const float*)d_in[6];
    const float* S2 = (const float*)d_in[7];
    const float* T2 = (const float*)d_in[8];
    const float* L  = (const float*)d_in[9];
    const float* bv = (const float*)d_in[10];
    const int*   be = (const int*)d_in[11];

    float* out = (float*)d_out;

    const size_t rows3 = (size_t)3 * NROW;
    const size_t nxt_n = (size_t)3 * BATCH;
    const size_t bkt_n = rows3 * CAP;

    const size_t ws_fast = (2 * rows3 + nxt_n + bkt_n) * sizeof(int)
                         + (size_t)BATCH * sizeof(float2)
                         + (size_t)BATCH * RDIM * sizeof(float);   // ~43.4 MB
    const size_t ws_mid  = (rows3 + nxt_n) * sizeof(int)
                         + (size_t)BATCH * sizeof(float2)
                         + (size_t)BATCH * RDIM * sizeof(float);   // ~21.8 MB

    if (ws_size >= ws_fast) {
        // ---- fast path: bucketed CSR, 2-row burst-issue apply ----
        int*    cnt    = (int*)d_ws;
        int*    head_  = cnt + rows3;
        int*    nxt    = head_ + rows3;
        int*    bucket = nxt + nxt_n;
        float2* scal   = (float2*)(bucket + bkt_n);
        float*  LpBuf  = (float*)(scal + BATCH);

        // cnt=0 and head=0 (idx+1 encoding) in ONE memset
        hipMemsetAsync(cnt, 0, 2 * rows3 * sizeof(int), stream);

        int pblocks = (BATCH * 8 + 255) / 256;    // 4096
        em_pre_bkt<<<pblocks, 256, 0, stream>>>(U0, U1, U2, L, bv, be,
                                                cnt, head_, nxt, bucket,
                                                scal, LpBuf);

        long athreads = (long)HALFROWS * 8;       // 2.4M
        int  ablocks  = (int)((athreads + 255) / 256);  // 9375
        em_apply_x2<<<ablocks, 256, 0, stream>>>(U0, U1, U2, S0, S1, S2,
                                                 T0, T1, T2, cnt, head_, nxt,
                                                 bucket, scal, LpBuf, out);
    } else if (ws_size >= ws_mid) {
        // ---- fallback: linked-list version ----
        int*    head_ = (int*)d_ws;
        int*    nxt   = head_ + rows3;
        float2* scal  = (float2*)(nxt + nxt_n);
        float*  LpBuf = (float*)(scal + BATCH);

        hipMemsetAsync(head_, 0, rows3 * sizeof(int), stream);

        int pblocks = (BATCH * 8 + 255) / 256;
        em_pre<<<pblocks, 256, 0, stream>>>(U0, U1, U2, L, bv, be,
                                            head_, nxt, scal, LpBuf);

        long athreads = 3L * NROW * 8;
        int  ablocks  = (int)((athreads + 255) / 256);
        em_apply_vec<<<ablocks, 256, 0, stream>>>(U0, U1, U2, S0, S1, S2,
                                                  T0, T1, T2, head_, nxt,
                                                  scal, LpBuf, out);
    }
}